// Round 2
// baseline (521.023 us; speedup 1.0000x reference)
//
#include <hip/hip_runtime.h>

typedef unsigned short u16;
typedef unsigned int u32;
typedef __attribute__((ext_vector_type(8))) short short8v;
typedef __attribute__((ext_vector_type(4))) float float4v;

__device__ __forceinline__ float sigm(float x) { return 1.0f / (1.0f + __expf(-x)); }
__device__ __forceinline__ u16 f2bf(float f) {
  u32 u = __float_as_uint(f);
  u32 r = (u + 0x7fffu + ((u >> 16) & 1u)) >> 16;
  return (u16)r;
}
__device__ __forceinline__ float bf2f(u16 w) { return __uint_as_float(((u32)w) << 16); }

__global__ void k_zero_i(int* __restrict__ p, int n) {
  int i = blockIdx.x * blockDim.x + threadIdx.x;
  if (i < n) p[i] = 0;
}

__global__ void k_cnt(const int* __restrict__ dst, int* __restrict__ cnt, int E) {
  int e = blockIdx.x * blockDim.x + threadIdx.x;
  if (e < E) atomicAdd(&cnt[dst[e]], 1);
}

// Exclusive prefix scan of cnt -> row[0..N]; row[N]=E. Single block, 256 thr.
__global__ void k_scan(const int* __restrict__ cnt, int* __restrict__ row, int N) {
  __shared__ int part[256];
  __shared__ int base[256];
  int t = threadIdx.x;
  int chunk = (N + 255) >> 8;
  int s0 = t * chunk;
  int s1 = min(s0 + chunk, N);
  int s = 0;
  for (int i = s0; i < s1; ++i) s += cnt[i];
  part[t] = s;
  __syncthreads();
  if (t == 0) {
    int run = 0;
    for (int i = 0; i < 256; ++i) { int v = part[i]; base[i] = run; run += v; }
  }
  __syncthreads();
  int run = base[t];
  for (int i = s0; i < s1; ++i) { row[i] = run; run += cnt[i]; }
  if (t == 255) row[N] = run;
}

__global__ void k_copy_i(const int* __restrict__ a, int* __restrict__ b, int n) {
  int i = blockIdx.x * blockDim.x + threadIdx.x;
  if (i < n) b[i] = a[i];
}

// Counting-sort edge ids by dst: perm[row[d]..row[d+1]) = {e : dst[e]==d}
__global__ void k_perm(const int* __restrict__ dst, int* __restrict__ cursor,
                       int* __restrict__ perm, int E) {
  int e = blockIdx.x * blockDim.x + threadIdx.x;
  if (e < E) {
    int p = atomicAdd(&cursor[dst[e]], 1);
    perm[p] = e;
  }
}

// h[n,f] = relu(sum_k x[n,k] * W_node[k,f] + b_node[f])   [verified r5-r18]
__global__ void k_node(const float* __restrict__ x, const float* __restrict__ Wn,
                       const float* __restrict__ bn, float* __restrict__ h, int N) {
  int tid = blockIdx.x * blockDim.x + threadIdx.x;
  if (tid >= N * 64) return;
  int n = tid >> 6, f = tid & 63;
  float acc = bn[f];
  for (int k = 0; k < 8; ++k) acc += x[(size_t)n * 8 + k] * Wn[k * 64 + f];
  h[tid] = fmaxf(acc, 0.0f);
}

// hmid -> plain bf16; 2 edges/block, ea computed once in LDS   [verified r18]
__global__ __launch_bounds__(256) void k_edge_mlp(
    const float* __restrict__ ea_in, const float* __restrict__ Wea,
    const float* __restrict__ bea, const float* __restrict__ We1,
    const float* __restrict__ be1, u16* __restrict__ Ahi, int E) {
  __shared__ float att[2][19];
  __shared__ float ea[2][12];
  int half = threadIdx.x >> 7;
  int t = threadIdx.x & 127;
  int e = blockIdx.x * 2 + half;
  bool real = (e < E);
  int ee = real ? e : E - 1;
  if (t < 19) att[half][t] = ea_in[(size_t)ee * 19 + t];
  __syncthreads();
  if (t < 12) {
    float a = bea[t];
#pragma unroll
    for (int k = 0; k < 19; ++k) a += att[half][k] * Wea[k * 12 + t];
    ea[half][t] = fmaxf(a, 0.0f);
  }
  __syncthreads();
  float a = be1[t];
#pragma unroll
  for (int j = 0; j < 12; ++j) a += ea[half][j] * We1[j * 128 + t];
  if (real) Ahi[(size_t)e * 128 + t] = f2bf(fmaxf(a, 0.0f));
}

// Pack W_e2 into MFMA-fragment-ordered bf16   [verified r9-r18]
__global__ void k_pack_b(const float* __restrict__ W2, u16* __restrict__ Bph) {
  int tid = blockIdx.x * blockDim.x + threadIdx.x;
  if (tid >= 128 * 4096) return;
  int j = tid & 7;
  int lane = (tid >> 3) & 63;
  int nt = (tid >> 9) & 3;
  int ks = (tid >> 11) & 3;
  int d = tid >> 13;
  int c = lane & 15, q = lane >> 4;
  int k = ks * 32 + q * 8 + j;
  int n = d * 64 + nt * 16 + c;
  Bph[tid] = f2bf(W2[(size_t)k * 4096 + n]);
}

// Pack GRU weights into MFMA B-fragment order   [verified r16-r18]
__global__ void k_prep_wtf(const float* __restrict__ Wih, const float* __restrict__ Whh,
                           u16* __restrict__ WpI, u16* __restrict__ WpH) {
  int tid = blockIdx.x * blockDim.x + threadIdx.x;
  if (tid >= 2 * 12288) return;
  int w = tid / 12288;
  int r = tid - w * 12288;
  int jj = r & 7;
  int lane = (r >> 3) & 63;
  int t = r >> 9;
  int nt = t % 12, ks = t / 12;
  int c = lane & 15, q = lane >> 4;
  int j = nt * 16 + c;
  int k = ks * 32 + q * 8 + jj;
  const float* W = w ? Whh : Wih;
  u16* Wp = w ? WpH : WpI;
  Wp[r] = f2bf(W[j * 64 + k]);
}

// Pack W_l1 (72x128, zero-padded K to 96) into MFMA B-fragment order
__global__ void k_prep_wl1(const float* __restrict__ Wl1, u16* __restrict__ Wp1) {
  int tid = blockIdx.x * blockDim.x + threadIdx.x;
  if (tid >= 3 * 8 * 64 * 8) return;
  int j = tid & 7;
  int lane = (tid >> 3) & 63;
  int nt = (tid >> 9) & 7;
  int ks = tid >> 12;
  int c = lane & 15, q = lane >> 4;
  int k = ks * 32 + q * 8 + j;
  int n = nt * 16 + c;
  Wp1[tid] = f2bf((k < 72) ? Wl1[k * 128 + n] : 0.0f);
}

// Fused conv, r20: ATOMIC-FREE. One block = 128 edges x all 64 d x 64 f.
// Clean per-edge msg stores; scatter-sum moved to CSR gather in k_gru_mfma.
// 4 waves = 2 m-groups (64 edges) x 2 f-groups (32 f); A frags in regs;
// B panel staged once/block/d via global_load_lds w16, double-buffered.
// LDS = 32768(Bdbuf) + 34816(hs 128x68 f32) + 8192(sb2 bf16) = 75776 B -> 2 blk/CU.
__global__ __launch_bounds__(256, 2) void k_conv_fused(
    const u16* __restrict__ Ahi, const u16* __restrict__ Bph,
    const float* __restrict__ b2, const float* __restrict__ h,
    const int* __restrict__ src, float* __restrict__ msgout, int E) {
  __shared__ __align__(16) u16 sB[2][8192];    // 2 x 16 KB B panels
  __shared__ __align__(16) float hs[128 * 68]; // h[src[e], 0:64], pad 68 (16B-aligned, 2-way banks)
  __shared__ __align__(16) u16 sb2h[4096];     // b2 as bf16
  int m0 = blockIdx.x * 128;
  int tid = threadIdx.x;
  int wave = tid >> 6, lane = tid & 63;
  int mw = wave >> 1, fw = wave & 1;
  int c = lane & 15, q = lane >> 4;

  auto stageB = [&](int d, int b) {
    const u16* gp = Bph + (size_t)d * 8192 + wave * 2048 + lane * 8;
    u16* lp = &sB[b][wave * 2048];
#pragma unroll
    for (int i = 0; i < 4; ++i)
      __builtin_amdgcn_global_load_lds(
          (const __attribute__((address_space(1))) unsigned int*)(gp + i * 512),
          (__attribute__((address_space(3))) unsigned int*)(lp + i * 512), 16, 0, 0);
  };

  stageB(0, 0);  // first panel in flight under the prologue

  // A fragments: 4 m-tiles x 4 k-slices, global->reg, held for whole kernel
  short8v afr[4][4];
#pragma unroll
  for (int mt = 0; mt < 4; ++mt) {
    int gr = m0 + mw * 64 + mt * 16 + c;
    if (gr >= E) gr = E - 1;
    const u16* ap = Ahi + (size_t)gr * 128 + q * 8;
#pragma unroll
    for (int ks = 0; ks < 4; ++ks) afr[mt][ks] = *(const short8v*)(ap + ks * 32);
  }

  // hs: h[src[e], 0:64] for all 128 edges (full d-range now)
#pragma unroll
  for (int p = 0; p < 8; ++p) {
    int slot = p * 256 + tid;
    int r = slot >> 4, s = slot & 15;
    int ge = m0 + r;
    if (ge >= E) ge = E - 1;
    int sn = src[ge];
    *(float4*)(&hs[r * 68 + s * 4]) = *(const float4*)(h + (size_t)sn * 64 + s * 4);
  }
  // sb2h: all 4096 b2 values as bf16
  {
    int t16 = tid * 16;
#pragma unroll
    for (int u = 0; u < 4; ++u) {
      float4 v = *(const float4*)(b2 + t16 + u * 4);
      sb2h[t16 + u * 4 + 0] = f2bf(v.x);
      sb2h[t16 + u * 4 + 1] = f2bf(v.y);
      sb2h[t16 + u * 4 + 2] = f2bf(v.z);
      sb2h[t16 + u * 4 + 3] = f2bf(v.w);
    }
  }
  __syncthreads();  // drains vmcnt: sB[0], hs, sb2h ready

  float msg[4][2][4];
#pragma unroll
  for (int mt = 0; mt < 4; ++mt)
#pragma unroll
    for (int nt = 0; nt < 2; ++nt)
#pragma unroll
      for (int r = 0; r < 4; ++r) msg[mt][nt][r] = 0.0f;

  int cur = 0;
  for (int dl = 0; dl < 64; ++dl) {
    if (dl < 63) stageB(dl + 1, cur ^ 1);
    float4v acc[4][2];
#pragma unroll
    for (int mt = 0; mt < 4; ++mt)
#pragma unroll
      for (int nt = 0; nt < 2; ++nt) acc[mt][nt] = (float4v){0.f, 0.f, 0.f, 0.f};
#pragma unroll
    for (int ks = 0; ks < 4; ++ks) {
      short8v b0 = *(const short8v*)(&sB[cur][ks * 2048 + fw * 1024 + lane * 8]);
      short8v b1 = *(const short8v*)(&sB[cur][ks * 2048 + fw * 1024 + 512 + lane * 8]);
#pragma unroll
      for (int mt = 0; mt < 4; ++mt) {
        acc[mt][0] = __builtin_amdgcn_mfma_f32_16x16x32_bf16(afr[mt][ks], b0, acc[mt][0], 0, 0, 0);
        acc[mt][1] = __builtin_amdgcn_mfma_f32_16x16x32_bf16(afr[mt][ks], b1, acc[mt][1], 0, 0, 0);
      }
    }
#pragma unroll
    for (int mt = 0; mt < 4; ++mt) {
      float hd[4];
#pragma unroll
      for (int r = 0; r < 4; ++r)
        hd[r] = hs[(mw * 64 + mt * 16 + q * 4 + r) * 68 + dl];  // broadcast over c
#pragma unroll
      for (int nt = 0; nt < 2; ++nt) {
        float b2v = bf2f(sb2h[dl * 64 + fw * 32 + nt * 16 + c]);
#pragma unroll
        for (int r = 0; r < 4; ++r) msg[mt][nt][r] += hd[r] * (acc[mt][nt][r] + b2v);
      }
    }
    __syncthreads();
    cur ^= 1;
  }

  // clean coalesced stores (atomic-free)
#pragma unroll
  for (int mt = 0; mt < 4; ++mt) {
#pragma unroll
    for (int r = 0; r < 4; ++r) {
      int e = m0 + mw * 64 + mt * 16 + q * 4 + r;
      if (e < E) {
        float* mp = msgout + (size_t)e * 64 + fw * 32 + c;
#pragma unroll
        for (int nt = 0; nt < 2; ++nt) mp[nt * 16] = msg[mt][nt][r];
      }
    }
  }
}

// MFMA GRU, r20: agg read replaced by CSR gather of msg rows (wave-uniform
// node -> coalesced 256B row reads, uniform deg loop). agg array deleted.
__global__ __launch_bounds__(256, 2) void k_gru_mfma(
    const float* __restrict__ msg, const int* __restrict__ perm,
    const int* __restrict__ row, const float* __restrict__ cb,
    const u16* __restrict__ WpI, const u16* __restrict__ WpH,
    const float* __restrict__ bih, const float* __restrict__ bhh,
    const float* __restrict__ hin, float* __restrict__ hout, int N) {
  __shared__ __align__(16) u16 sM[64 * 72];
  __shared__ __align__(16) u16 sH[64 * 72];
  __shared__ __align__(16) float sHf[64 * 68];
  int n0 = blockIdx.x * 64;
  int tid = threadIdx.x;
#pragma unroll
  for (int p = 0; p < 16; ++p) {
    int slot = p * 256 + tid;
    int n = slot >> 6, f = slot & 63;
    int gn = n0 + n;
    if (gn >= N) gn = N - 1;
    int b0 = row[gn], b1 = row[gn + 1];
    float av = 0.0f;
    for (int j = b0; j < b1; ++j) av += msg[(size_t)perm[j] * 64 + f];
    float cf = fmaxf((float)(b1 - b0), 1.0f);
    float m = fmaxf(av / cf + cb[f], 0.0f);
    float hv = hin[(size_t)gn * 64 + f];
    sM[n * 72 + f] = f2bf(m);
    sH[n * 72 + f] = f2bf(hv);
    sHf[n * 68 + f] = hv;
  }
  __syncthreads();
  int wave = tid >> 6, lane = tid & 63;
  int c = lane & 15, q = lane >> 4;
  short8v am[2], ah[2];
#pragma unroll
  for (int ks = 0; ks < 2; ++ks) {
    am[ks] = *(const short8v*)(&sM[(wave * 16 + c) * 72 + ks * 32 + q * 8]);
    ah[ks] = *(const short8v*)(&sH[(wave * 16 + c) * 72 + ks * 32 + q * 8]);
  }
  float4v accRZ[8], accN[4], accHN[4];
#pragma unroll
  for (int i = 0; i < 8; ++i) accRZ[i] = (float4v){0.f, 0.f, 0.f, 0.f};
#pragma unroll
  for (int i = 0; i < 4; ++i) {
    accN[i] = (float4v){0.f, 0.f, 0.f, 0.f};
    accHN[i] = (float4v){0.f, 0.f, 0.f, 0.f};
  }
#pragma unroll
  for (int ks = 0; ks < 2; ++ks) {
#pragma unroll
    for (int nt = 0; nt < 8; ++nt) {
      short8v bI = *(const short8v*)(WpI + ((size_t)(ks * 12 + nt) * 64 + lane) * 8);
      short8v bH = *(const short8v*)(WpH + ((size_t)(ks * 12 + nt) * 64 + lane) * 8);
      accRZ[nt] = __builtin_amdgcn_mfma_f32_16x16x32_bf16(am[ks], bI, accRZ[nt], 0, 0, 0);
      accRZ[nt] = __builtin_amdgcn_mfma_f32_16x16x32_bf16(ah[ks], bH, accRZ[nt], 0, 0, 0);
    }
#pragma unroll
    for (int nt = 0; nt < 4; ++nt) {
      short8v bI = *(const short8v*)(WpI + ((size_t)(ks * 12 + 8 + nt) * 64 + lane) * 8);
      short8v bH = *(const short8v*)(WpH + ((size_t)(ks * 12 + 8 + nt) * 64 + lane) * 8);
      accN[nt] = __builtin_amdgcn_mfma_f32_16x16x32_bf16(am[ks], bI, accN[nt], 0, 0, 0);
      accHN[nt] = __builtin_amdgcn_mfma_f32_16x16x32_bf16(ah[ks], bH, accHN[nt], 0, 0, 0);
    }
  }
#pragma unroll
  for (int nt = 0; nt < 4; ++nt) {
    int f = nt * 16 + c;
    float brz_r = bih[f] + bhh[f];
    float brz_z = bih[64 + f] + bhh[64 + f];
    float bin = bih[128 + f];
    float bhn = bhh[128 + f];
#pragma unroll
    for (int r = 0; r < 4; ++r) {
      int nl = wave * 16 + q * 4 + r;
      int gn = n0 + nl;
      float rr = sigm(accRZ[nt][r] + brz_r);
      float zz = sigm(accRZ[nt + 4][r] + brz_z);
      float ng = tanhf(accN[nt][r] + bin + rr * (accHN[nt][r] + bhn));
      float hv = sHf[nl * 68 + f];
      if (gn < N) hout[(size_t)gn * 64 + f] = (1.0f - zz) * ng + zz * hv;
    }
  }
}

// MFMA final MLP: 64 edges/block   [verified r18]
__global__ __launch_bounds__(256) void k_final_mfma(
    const float* __restrict__ h, const float* __restrict__ ea3,
    const int* __restrict__ idx3, const u16* __restrict__ Wp1,
    const float* __restrict__ bl1, const float* __restrict__ Wl2,
    const float* __restrict__ bl2, float* __restrict__ out, int E3) {
  __shared__ __align__(16) u16 sF[64 * 104];
  int e0 = blockIdx.x * 64;
  int tid = threadIdx.x;
  {
    int er = tid >> 2;
    int part = tid & 3;
    int ge = e0 + er;
    int gc = (ge < E3) ? ge : E3 - 1;
    int a = idx3[gc], b = idx3[E3 + gc];
    for (int kk = part * 24; kk < part * 24 + 24; ++kk) {
      float v;
      if (kk < 64) v = 0.5f * (h[(size_t)a * 64 + kk] + h[(size_t)b * 64 + kk]);
      else if (kk < 72) v = ea3[(size_t)gc * 8 + (kk - 64)];
      else v = 0.0f;
      sF[er * 104 + kk] = f2bf(v);
    }
  }
  __syncthreads();
  int wave = tid >> 6, lane = tid & 63;
  int c = lane & 15, q = lane >> 4;
  float4v acc[8];
#pragma unroll
  for (int nt = 0; nt < 8; ++nt) acc[nt] = (float4v){0.f, 0.f, 0.f, 0.f};
#pragma unroll
  for (int ks = 0; ks < 3; ++ks) {
    short8v af = *(const short8v*)(&sF[(wave * 16 + c) * 104 + ks * 32 + q * 8]);
#pragma unroll
    for (int nt = 0; nt < 8; ++nt) {
      short8v bf = *(const short8v*)(Wp1 + ((size_t)(ks * 8 + nt) * 64 + lane) * 8);
      acc[nt] = __builtin_amdgcn_mfma_f32_16x16x32_bf16(af, bf, acc[nt], 0, 0, 0);
    }
  }
  float v[4] = {0.f, 0.f, 0.f, 0.f};
#pragma unroll
  for (int nt = 0; nt < 8; ++nt) {
    int n = nt * 16 + c;
    float b1 = bl1[n];
    float w2 = Wl2[n];
#pragma unroll
    for (int r = 0; r < 4; ++r) v[r] += fmaxf(acc[nt][r] + b1, 0.0f) * w2;
  }
#pragma unroll
  for (int off = 1; off < 16; off <<= 1) {
#pragma unroll
    for (int r = 0; r < 4; ++r) v[r] += __shfl_xor(v[r], off);
  }
  if (c == 0) {
    float b2v = bl2[0];
#pragma unroll
    for (int r = 0; r < 4; ++r) {
      int e = e0 + wave * 16 + q * 4 + r;
      if (e < E3) out[e] = v[r] + b2v;
    }
  }
}

extern "C" void kernel_launch(void* const* d_in, const int* in_sizes, int n_in,
                              void* d_out, int out_size, void* d_ws, size_t ws_size,
                              hipStream_t stream) {
  const float* x          = (const float*)d_in[0];
  const float* edge_attr  = (const float*)d_in[1];
  const float* edge_attr3 = (const float*)d_in[2];
  const int*   edge_index = (const int*)d_in[3];
  const int*   edge_index3= (const int*)d_in[4];
  const float* W_node = (const float*)d_in[5];
  const float* b_node = (const float*)d_in[6];
  const float* W_ea   = (const float*)d_in[7];
  const float* b_ea   = (const float*)d_in[8];
  const float* W_e1   = (const float*)d_in[9];
  const float* b_e1   = (const float*)d_in[10];
  const float* W_e2   = (const float*)d_in[11];
  const float* b_e2   = (const float*)d_in[12];
  const float* conv_bias = (const float*)d_in[13];
  const float* W_ih   = (const float*)d_in[14];
  const float* b_ih   = (const float*)d_in[15];
  const float* W_hh   = (const float*)d_in[16];
  const float* b_hh   = (const float*)d_in[17];
  const float* W_l1   = (const float*)d_in[18];
  const float* b_l1   = (const float*)d_in[19];
  const float* W_l2   = (const float*)d_in[20];
  const float* b_l2   = (const float*)d_in[21];

  int N  = in_sizes[0] / 8;
  int E  = in_sizes[1] / 19;
  int E3 = in_sizes[2] / 8;

  char* p = (char*)d_ws;
  auto carve = [&](size_t bytes) -> void* {
    char* q = p;
    p += (bytes + 255) & ~(size_t)255;
    return (void*)q;
  };
  float* hA    = (float*)carve((size_t)N * 64 * 4);
  float* hB    = (float*)carve((size_t)N * 64 * 4);
  float* msg   = (float*)carve((size_t)E * 64 * 4);
  int*   cnt   = (int*)carve((size_t)N * 4);
  int*   row   = (int*)carve((size_t)(N + 1) * 4);
  int*   cursor= (int*)carve((size_t)N * 4);
  int*   perm  = (int*)carve((size_t)E * 4);
  u16*   Ahi   = (u16*)carve((size_t)E * 128 * 2);
  u16*   Bph   = (u16*)carve((size_t)128 * 4096 * 2);
  u16*   WpI   = (u16*)carve(12288 * 2);
  u16*   WpH   = (u16*)carve(12288 * 2);
  u16*   Wp1   = (u16*)carve(12288 * 2);

  const int* src = edge_index;
  const int* dst = edge_index + E;

  // CSR build (once): cnt -> row (scan) -> perm (counting sort by dst)
  k_zero_i<<<(N + 255) / 256, 256, 0, stream>>>(cnt, N);
  k_cnt<<<(E + 255) / 256, 256, 0, stream>>>(dst, cnt, E);
  k_scan<<<1, 256, 0, stream>>>(cnt, row, N);
  k_copy_i<<<(N + 255) / 256, 256, 0, stream>>>(row, cursor, N);
  k_perm<<<(E + 255) / 256, 256, 0, stream>>>(dst, cursor, perm, E);

  k_node<<<((size_t)N * 64 + 255) / 256, 256, 0, stream>>>(x, W_node, b_node, hA, N);
  k_edge_mlp<<<(E + 1) / 2, 256, 0, stream>>>(edge_attr, W_ea, b_ea, W_e1, b_e1, Ahi, E);
  k_pack_b<<<(128 * 4096 + 255) / 256, 256, 0, stream>>>(W_e2, Bph);
  k_prep_wtf<<<(2 * 12288 + 255) / 256, 256, 0, stream>>>(W_ih, W_hh, WpI, WpH);
  k_prep_wl1<<<(12288 + 255) / 256, 256, 0, stream>>>(W_l1, Wp1);

  float* hcur = hA;
  float* hnxt = hB;
  int gconv = (E + 127) / 128;
  int ngru = (N + 63) / 64;
  for (int it = 0; it < 3; ++it) {
    k_conv_fused<<<gconv, 256, 0, stream>>>(Ahi, Bph, b_e2, hcur, src, msg, E);
    k_gru_mfma<<<ngru, 256, 0, stream>>>(msg, perm, row, conv_bias, WpI, WpH,
                                         b_ih, b_hh, hcur, hnxt, N);
    float* tmp = hcur; hcur = hnxt; hnxt = tmp;
  }
  k_final_mfma<<<(E3 + 63) / 64, 256, 0, stream>>>(hcur, edge_attr3, edge_index3, Wp1,
                                                   b_l1, W_l2, b_l2, (float*)d_out, E3);
}

// Round 3
// 487.781 us; speedup vs baseline: 1.0681x; 1.0681x over previous
//
#include <hip/hip_runtime.h>

typedef unsigned short u16;
typedef unsigned int u32;
typedef __attribute__((ext_vector_type(8))) short short8v;
typedef __attribute__((ext_vector_type(4))) float float4v;

__device__ __forceinline__ float sigm(float x) { return 1.0f / (1.0f + __expf(-x)); }
__device__ __forceinline__ u16 f2bf(float f) {
  u32 u = __float_as_uint(f);
  u32 r = (u + 0x7fffu + ((u >> 16) & 1u)) >> 16;
  return (u16)r;
}
__device__ __forceinline__ float bf2f(u16 w) { return __uint_as_float(((u32)w) << 16); }

__global__ void k_zero_i(int* __restrict__ p, int n) {
  int i = blockIdx.x * blockDim.x + threadIdx.x;
  if (i < n) p[i] = 0;
}

__global__ void k_cnt(const int* __restrict__ dst, int* __restrict__ cnt, int E) {
  int e = blockIdx.x * blockDim.x + threadIdx.x;
  if (e < E) atomicAdd(&cnt[dst[e]], 1);
}

// Exclusive prefix scan of cnt -> row[0..N]; row[N]=E. Single block, 256 thr.
__global__ void k_scan(const int* __restrict__ cnt, int* __restrict__ row, int N) {
  __shared__ int part[256];
  __shared__ int base[256];
  int t = threadIdx.x;
  int chunk = (N + 255) >> 8;
  int s0 = t * chunk;
  int s1 = min(s0 + chunk, N);
  int s = 0;
  for (int i = s0; i < s1; ++i) s += cnt[i];
  part[t] = s;
  __syncthreads();
  if (t == 0) {
    int run = 0;
    for (int i = 0; i < 256; ++i) { int v = part[i]; base[i] = run; run += v; }
  }
  __syncthreads();
  int run = base[t];
  for (int i = s0; i < s1; ++i) { row[i] = run; run += cnt[i]; }
  if (t == 255) row[N] = run;
}

__global__ void k_copy_i(const int* __restrict__ a, int* __restrict__ b, int n) {
  int i = blockIdx.x * blockDim.x + threadIdx.x;
  if (i < n) b[i] = a[i];
}

// pos[e] = CSR slot of edge e among edges with same dst (counting sort position)
__global__ void k_pos(const int* __restrict__ dst, int* __restrict__ cursor,
                      int* __restrict__ pos, int E) {
  int e = blockIdx.x * blockDim.x + threadIdx.x;
  if (e < E) pos[e] = atomicAdd(&cursor[dst[e]], 1);
}

// h[n,f] = relu(sum_k x[n,k] * W_node[k,f] + b_node[f])   [verified r5-r18]
__global__ void k_node(const float* __restrict__ x, const float* __restrict__ Wn,
                       const float* __restrict__ bn, float* __restrict__ h, int N) {
  int tid = blockIdx.x * blockDim.x + threadIdx.x;
  if (tid >= N * 64) return;
  int n = tid >> 6, f = tid & 63;
  float acc = bn[f];
  for (int k = 0; k < 8; ++k) acc += x[(size_t)n * 8 + k] * Wn[k * 64 + f];
  h[tid] = fmaxf(acc, 0.0f);
}

// hmid -> plain bf16; 2 edges/block, ea computed once in LDS   [verified r18]
__global__ __launch_bounds__(256) void k_edge_mlp(
    const float* __restrict__ ea_in, const float* __restrict__ Wea,
    const float* __restrict__ bea, const float* __restrict__ We1,
    const float* __restrict__ be1, u16* __restrict__ Ahi, int E) {
  __shared__ float att[2][19];
  __shared__ float ea[2][12];
  int half = threadIdx.x >> 7;
  int t = threadIdx.x & 127;
  int e = blockIdx.x * 2 + half;
  bool real = (e < E);
  int ee = real ? e : E - 1;
  if (t < 19) att[half][t] = ea_in[(size_t)ee * 19 + t];
  __syncthreads();
  if (t < 12) {
    float a = bea[t];
#pragma unroll
    for (int k = 0; k < 19; ++k) a += att[half][k] * Wea[k * 12 + t];
    ea[half][t] = fmaxf(a, 0.0f);
  }
  __syncthreads();
  float a = be1[t];
#pragma unroll
  for (int j = 0; j < 12; ++j) a += ea[half][j] * We1[j * 128 + t];
  if (real) Ahi[(size_t)e * 128 + t] = f2bf(fmaxf(a, 0.0f));
}

// Pack W_e2 into MFMA-fragment-ordered bf16   [verified r9-r18]
__global__ void k_pack_b(const float* __restrict__ W2, u16* __restrict__ Bph) {
  int tid = blockIdx.x * blockDim.x + threadIdx.x;
  if (tid >= 128 * 4096) return;
  int j = tid & 7;
  int lane = (tid >> 3) & 63;
  int nt = (tid >> 9) & 3;
  int ks = (tid >> 11) & 3;
  int d = tid >> 13;
  int c = lane & 15, q = lane >> 4;
  int k = ks * 32 + q * 8 + j;
  int n = d * 64 + nt * 16 + c;
  Bph[tid] = f2bf(W2[(size_t)k * 4096 + n]);
}

// Pack GRU weights into MFMA B-fragment order   [verified r16-r18]
__global__ void k_prep_wtf(const float* __restrict__ Wih, const float* __restrict__ Whh,
                           u16* __restrict__ WpI, u16* __restrict__ WpH) {
  int tid = blockIdx.x * blockDim.x + threadIdx.x;
  if (tid >= 2 * 12288) return;
  int w = tid / 12288;
  int r = tid - w * 12288;
  int jj = r & 7;
  int lane = (r >> 3) & 63;
  int t = r >> 9;
  int nt = t % 12, ks = t / 12;
  int c = lane & 15, q = lane >> 4;
  int j = nt * 16 + c;
  int k = ks * 32 + q * 8 + jj;
  const float* W = w ? Whh : Wih;
  u16* Wp = w ? WpH : WpI;
  Wp[r] = f2bf(W[j * 64 + k]);
}

// Pack W_l1 (72x128, zero-padded K to 96) into MFMA B-fragment order
__global__ void k_prep_wl1(const float* __restrict__ Wl1, u16* __restrict__ Wp1) {
  int tid = blockIdx.x * blockDim.x + threadIdx.x;
  if (tid >= 3 * 8 * 64 * 8) return;
  int j = tid & 7;
  int lane = (tid >> 3) & 63;
  int nt = (tid >> 9) & 7;
  int ks = tid >> 12;
  int c = lane & 15, q = lane >> 4;
  int k = ks * 32 + q * 8 + j;
  int n = nt * 16 + c;
  Wp1[tid] = f2bf((k < 72) ? Wl1[k * 128 + n] : 0.0f);
}

// Fused conv, r21. LDS-pipe rebalance:
//  - hsT[d][edge] transposed h-stage: hd[0..3] = ONE ds_read_b128 per mt
//    (was 16 scalar ds_read_b32/wave/iter -> 4 b128; LDS pipe 742->384 cyc/CU-iter)
//  - b2v hoisted out of mt loop (8 -> 2 LDS reads/wave/iter)
//  - setprio(1) around MFMA cluster (T5)
//  - msg rows stored PRE-PERMUTED via pos[e] so GRU gathers contiguous rows
// LDS = 32768(Bdbuf) + 33792(hsT 64x132 f32) + 8192(sb2h) = 74752 B -> 2 blk/CU.
__global__ __launch_bounds__(256, 2) void k_conv_fused(
    const u16* __restrict__ Ahi, const u16* __restrict__ Bph,
    const float* __restrict__ b2, const float* __restrict__ h,
    const int* __restrict__ src, const int* __restrict__ pos,
    float* __restrict__ msgp, int E) {
  __shared__ __align__(16) u16 sB[2][8192];     // 2 x 16 KB B panels
  __shared__ __align__(16) float hsT[64 * 132]; // h[src[e], d] transposed: [d][edge]
  __shared__ __align__(16) u16 sb2h[4096];      // b2 as bf16
  int m0 = blockIdx.x * 128;
  int tid = threadIdx.x;
  int wave = tid >> 6, lane = tid & 63;
  int mw = wave >> 1, fw = wave & 1;
  int c = lane & 15, q = lane >> 4;

  auto stageB = [&](int d, int b) {
    const u16* gp = Bph + (size_t)d * 8192 + wave * 2048 + lane * 8;
    u16* lp = &sB[b][wave * 2048];
#pragma unroll
    for (int i = 0; i < 4; ++i)
      __builtin_amdgcn_global_load_lds(
          (const __attribute__((address_space(1))) unsigned int*)(gp + i * 512),
          (__attribute__((address_space(3))) unsigned int*)(lp + i * 512), 16, 0, 0);
  };

  stageB(0, 0);  // first panel in flight under the prologue

  // A fragments: 4 m-tiles x 4 k-slices, global->reg, held for whole kernel
  short8v afr[4][4];
#pragma unroll
  for (int mt = 0; mt < 4; ++mt) {
    int gr = m0 + mw * 64 + mt * 16 + c;
    if (gr >= E) gr = E - 1;
    const u16* ap = Ahi + (size_t)gr * 128 + q * 8;
#pragma unroll
    for (int ks = 0; ks < 4; ++ks) afr[mt][ks] = *(const short8v*)(ap + ks * 32);
  }

  // hsT: transposed stage of h[src[e], 0:64] (one-time 8-way-conflict writes, amortized)
#pragma unroll
  for (int p = 0; p < 8; ++p) {
    int slot = p * 256 + tid;
    int r = slot >> 4, s = slot & 15;  // edge r, d-quad s
    int ge = m0 + r;
    if (ge >= E) ge = E - 1;
    int sn = src[ge];
    float4 v = *(const float4*)(h + (size_t)sn * 64 + s * 4);
    hsT[(s * 4 + 0) * 132 + r] = v.x;
    hsT[(s * 4 + 1) * 132 + r] = v.y;
    hsT[(s * 4 + 2) * 132 + r] = v.z;
    hsT[(s * 4 + 3) * 132 + r] = v.w;
  }
  // sb2h: all 4096 b2 values as bf16
  {
    int t16 = tid * 16;
#pragma unroll
    for (int u = 0; u < 4; ++u) {
      float4 v = *(const float4*)(b2 + t16 + u * 4);
      sb2h[t16 + u * 4 + 0] = f2bf(v.x);
      sb2h[t16 + u * 4 + 1] = f2bf(v.y);
      sb2h[t16 + u * 4 + 2] = f2bf(v.z);
      sb2h[t16 + u * 4 + 3] = f2bf(v.w);
    }
  }
  __syncthreads();  // drains vmcnt: sB[0], hsT, sb2h ready

  float msg[4][2][4];
#pragma unroll
  for (int mt = 0; mt < 4; ++mt)
#pragma unroll
    for (int nt = 0; nt < 2; ++nt)
#pragma unroll
      for (int r = 0; r < 4; ++r) msg[mt][nt][r] = 0.0f;

  int cur = 0;
  for (int dl = 0; dl < 64; ++dl) {
    if (dl < 63) stageB(dl + 1, cur ^ 1);
    // b2v hoisted: one pair per iter (was re-read per mt)
    float b2v0 = bf2f(sb2h[dl * 64 + fw * 32 + c]);
    float b2v1 = bf2f(sb2h[dl * 64 + fw * 32 + 16 + c]);
    float4v acc[4][2];
#pragma unroll
    for (int mt = 0; mt < 4; ++mt)
#pragma unroll
      for (int nt = 0; nt < 2; ++nt) acc[mt][nt] = (float4v){0.f, 0.f, 0.f, 0.f};
    __builtin_amdgcn_s_setprio(1);
#pragma unroll
    for (int ks = 0; ks < 4; ++ks) {
      short8v b0 = *(const short8v*)(&sB[cur][ks * 2048 + fw * 1024 + lane * 8]);
      short8v b1 = *(const short8v*)(&sB[cur][ks * 2048 + fw * 1024 + 512 + lane * 8]);
#pragma unroll
      for (int mt = 0; mt < 4; ++mt) {
        acc[mt][0] = __builtin_amdgcn_mfma_f32_16x16x32_bf16(afr[mt][ks], b0, acc[mt][0], 0, 0, 0);
        acc[mt][1] = __builtin_amdgcn_mfma_f32_16x16x32_bf16(afr[mt][ks], b1, acc[mt][1], 0, 0, 0);
      }
    }
    __builtin_amdgcn_s_setprio(0);
#pragma unroll
    for (int mt = 0; mt < 4; ++mt) {
      // hd for 4 rows = one contiguous b128 (hsT layout), broadcast over c
      float4 hd4 = *(const float4*)(&hsT[dl * 132 + mw * 64 + mt * 16 + q * 4]);
      float hd[4] = {hd4.x, hd4.y, hd4.z, hd4.w};
#pragma unroll
      for (int r = 0; r < 4; ++r) {
        msg[mt][0][r] += hd[r] * (acc[mt][0][r] + b2v0);
        msg[mt][1][r] += hd[r] * (acc[mt][1][r] + b2v1);
      }
    }
    __syncthreads();
    cur ^= 1;
  }

  // stores pre-permuted to CSR slot order: GRU reads contiguous rows
#pragma unroll
  for (int mt = 0; mt < 4; ++mt) {
#pragma unroll
    for (int r = 0; r < 4; ++r) {
      int e = m0 + mw * 64 + mt * 16 + q * 4 + r;
      if (e < E) {
        int pe = pos[e];
        float* mp = msgp + (size_t)pe * 64 + fw * 32 + c;
#pragma unroll
        for (int nt = 0; nt < 2; ++nt) mp[nt * 16] = msg[mt][nt][r];
      }
    }
  }
}

// MFMA GRU, r21: contiguous CSR-row gather (msgp pre-permuted by conv).
__global__ __launch_bounds__(256, 2) void k_gru_mfma(
    const float* __restrict__ msgp, const int* __restrict__ row,
    const float* __restrict__ cb, const u16* __restrict__ WpI,
    const u16* __restrict__ WpH, const float* __restrict__ bih,
    const float* __restrict__ bhh, const float* __restrict__ hin,
    float* __restrict__ hout, int N) {
  __shared__ __align__(16) u16 sM[64 * 72];
  __shared__ __align__(16) u16 sH[64 * 72];
  __shared__ __align__(16) float sHf[64 * 68];
  int n0 = blockIdx.x * 64;
  int tid = threadIdx.x;
#pragma unroll
  for (int p = 0; p < 16; ++p) {
    int slot = p * 256 + tid;
    int n = slot >> 6, f = slot & 63;
    int gn = n0 + n;
    if (gn >= N) gn = N - 1;
    int b0 = row[gn], b1 = row[gn + 1];
    float av = 0.0f;
    for (int j = b0; j < b1; ++j) av += msgp[(size_t)j * 64 + f];
    float cf = fmaxf((float)(b1 - b0), 1.0f);
    float m = fmaxf(av / cf + cb[f], 0.0f);
    float hv = hin[(size_t)gn * 64 + f];
    sM[n * 72 + f] = f2bf(m);
    sH[n * 72 + f] = f2bf(hv);
    sHf[n * 68 + f] = hv;
  }
  __syncthreads();
  int wave = tid >> 6, lane = tid & 63;
  int c = lane & 15, q = lane >> 4;
  short8v am[2], ah[2];
#pragma unroll
  for (int ks = 0; ks < 2; ++ks) {
    am[ks] = *(const short8v*)(&sM[(wave * 16 + c) * 72 + ks * 32 + q * 8]);
    ah[ks] = *(const short8v*)(&sH[(wave * 16 + c) * 72 + ks * 32 + q * 8]);
  }
  float4v accRZ[8], accN[4], accHN[4];
#pragma unroll
  for (int i = 0; i < 8; ++i) accRZ[i] = (float4v){0.f, 0.f, 0.f, 0.f};
#pragma unroll
  for (int i = 0; i < 4; ++i) {
    accN[i] = (float4v){0.f, 0.f, 0.f, 0.f};
    accHN[i] = (float4v){0.f, 0.f, 0.f, 0.f};
  }
#pragma unroll
  for (int ks = 0; ks < 2; ++ks) {
#pragma unroll
    for (int nt = 0; nt < 8; ++nt) {
      short8v bI = *(const short8v*)(WpI + ((size_t)(ks * 12 + nt) * 64 + lane) * 8);
      short8v bH = *(const short8v*)(WpH + ((size_t)(ks * 12 + nt) * 64 + lane) * 8);
      accRZ[nt] = __builtin_amdgcn_mfma_f32_16x16x32_bf16(am[ks], bI, accRZ[nt], 0, 0, 0);
      accRZ[nt] = __builtin_amdgcn_mfma_f32_16x16x32_bf16(ah[ks], bH, accRZ[nt], 0, 0, 0);
    }
#pragma unroll
    for (int nt = 0; nt < 4; ++nt) {
      short8v bI = *(const short8v*)(WpI + ((size_t)(ks * 12 + 8 + nt) * 64 + lane) * 8);
      short8v bH = *(const short8v*)(WpH + ((size_t)(ks * 12 + 8 + nt) * 64 + lane) * 8);
      accN[nt] = __builtin_amdgcn_mfma_f32_16x16x32_bf16(am[ks], bI, accN[nt], 0, 0, 0);
      accHN[nt] = __builtin_amdgcn_mfma_f32_16x16x32_bf16(ah[ks], bH, accHN[nt], 0, 0, 0);
    }
  }
#pragma unroll
  for (int nt = 0; nt < 4; ++nt) {
    int f = nt * 16 + c;
    float brz_r = bih[f] + bhh[f];
    float brz_z = bih[64 + f] + bhh[64 + f];
    float bin = bih[128 + f];
    float bhn = bhh[128 + f];
#pragma unroll
    for (int r = 0; r < 4; ++r) {
      int nl = wave * 16 + q * 4 + r;
      int gn = n0 + nl;
      float rr = sigm(accRZ[nt][r] + brz_r);
      float zz = sigm(accRZ[nt + 4][r] + brz_z);
      float ng = tanhf(accN[nt][r] + bin + rr * (accHN[nt][r] + bhn));
      float hv = sHf[nl * 68 + f];
      if (gn < N) hout[(size_t)gn * 64 + f] = (1.0f - zz) * ng + zz * hv;
    }
  }
}

// MFMA final MLP: 64 edges/block   [verified r18]
__global__ __launch_bounds__(256) void k_final_mfma(
    const float* __restrict__ h, const float* __restrict__ ea3,
    const int* __restrict__ idx3, const u16* __restrict__ Wp1,
    const float* __restrict__ bl1, const float* __restrict__ Wl2,
    const float* __restrict__ bl2, float* __restrict__ out, int E3) {
  __shared__ __align__(16) u16 sF[64 * 104];
  int e0 = blockIdx.x * 64;
  int tid = threadIdx.x;
  {
    int er = tid >> 2;
    int part = tid & 3;
    int ge = e0 + er;
    int gc = (ge < E3) ? ge : E3 - 1;
    int a = idx3[gc], b = idx3[E3 + gc];
    for (int kk = part * 24; kk < part * 24 + 24; ++kk) {
      float v;
      if (kk < 64) v = 0.5f * (h[(size_t)a * 64 + kk] + h[(size_t)b * 64 + kk]);
      else if (kk < 72) v = ea3[(size_t)gc * 8 + (kk - 64)];
      else v = 0.0f;
      sF[er * 104 + kk] = f2bf(v);
    }
  }
  __syncthreads();
  int wave = tid >> 6, lane = tid & 63;
  int c = lane & 15, q = lane >> 4;
  float4v acc[8];
#pragma unroll
  for (int nt = 0; nt < 8; ++nt) acc[nt] = (float4v){0.f, 0.f, 0.f, 0.f};
#pragma unroll
  for (int ks = 0; ks < 3; ++ks) {
    short8v af = *(const short8v*)(&sF[(wave * 16 + c) * 104 + ks * 32 + q * 8]);
#pragma unroll
    for (int nt = 0; nt < 8; ++nt) {
      short8v bf = *(const short8v*)(Wp1 + ((size_t)(ks * 8 + nt) * 64 + lane) * 8);
      acc[nt] = __builtin_amdgcn_mfma_f32_16x16x32_bf16(af, bf, acc[nt], 0, 0, 0);
    }
  }
  float v[4] = {0.f, 0.f, 0.f, 0.f};
#pragma unroll
  for (int nt = 0; nt < 8; ++nt) {
    int n = nt * 16 + c;
    float b1 = bl1[n];
    float w2 = Wl2[n];
#pragma unroll
    for (int r = 0; r < 4; ++r) v[r] += fmaxf(acc[nt][r] + b1, 0.0f) * w2;
  }
#pragma unroll
  for (int off = 1; off < 16; off <<= 1) {
#pragma unroll
    for (int r = 0; r < 4; ++r) v[r] += __shfl_xor(v[r], off);
  }
  if (c == 0) {
    float b2v = bl2[0];
#pragma unroll
    for (int r = 0; r < 4; ++r) {
      int e = e0 + wave * 16 + q * 4 + r;
      if (e < E3) out[e] = v[r] + b2v;
    }
  }
}

extern "C" void kernel_launch(void* const* d_in, const int* in_sizes, int n_in,
                              void* d_out, int out_size, void* d_ws, size_t ws_size,
                              hipStream_t stream) {
  const float* x          = (const float*)d_in[0];
  const float* edge_attr  = (const float*)d_in[1];
  const float* edge_attr3 = (const float*)d_in[2];
  const int*   edge_index = (const int*)d_in[3];
  const int*   edge_index3= (const int*)d_in[4];
  const float* W_node = (const float*)d_in[5];
  const float* b_node = (const float*)d_in[6];
  const float* W_ea   = (const float*)d_in[7];
  const float* b_ea   = (const float*)d_in[8];
  const float* W_e1   = (const float*)d_in[9];
  const float* b_e1   = (const float*)d_in[10];
  const float* W_e2   = (const float*)d_in[11];
  const float* b_e2   = (const float*)d_in[12];
  const float* conv_bias = (const float*)d_in[13];
  const float* W_ih   = (const float*)d_in[14];
  const float* b_ih   = (const float*)d_in[15];
  const float* W_hh   = (const float*)d_in[16];
  const float* b_hh   = (const float*)d_in[17];
  const float* W_l1   = (const float*)d_in[18];
  const float* b_l1   = (const float*)d_in[19];
  const float* W_l2   = (const float*)d_in[20];
  const float* b_l2   = (const float*)d_in[21];

  int N  = in_sizes[0] / 8;
  int E  = in_sizes[1] / 19;
  int E3 = in_sizes[2] / 8;

  char* p = (char*)d_ws;
  auto carve = [&](size_t bytes) -> void* {
    char* q = p;
    p += (bytes + 255) & ~(size_t)255;
    return (void*)q;
  };
  float* hA    = (float*)carve((size_t)N * 64 * 4);
  float* hB    = (float*)carve((size_t)N * 64 * 4);
  float* msgp  = (float*)carve((size_t)E * 64 * 4);
  int*   cnt   = (int*)carve((size_t)N * 4);
  int*   row   = (int*)carve((size_t)(N + 1) * 4);
  int*   cursor= (int*)carve((size_t)N * 4);
  int*   pos   = (int*)carve((size_t)E * 4);
  u16*   Ahi   = (u16*)carve((size_t)E * 128 * 2);
  u16*   Bph   = (u16*)carve((size_t)128 * 4096 * 2);
  u16*   WpI   = (u16*)carve(12288 * 2);
  u16*   WpH   = (u16*)carve(12288 * 2);
  u16*   Wp1   = (u16*)carve(12288 * 2);

  const int* src = edge_index;
  const int* dst = edge_index + E;

  // CSR build (once): cnt -> row (scan) -> pos (counting-sort slot per edge)
  k_zero_i<<<(N + 255) / 256, 256, 0, stream>>>(cnt, N);
  k_cnt<<<(E + 255) / 256, 256, 0, stream>>>(dst, cnt, E);
  k_scan<<<1, 256, 0, stream>>>(cnt, row, N);
  k_copy_i<<<(N + 255) / 256, 256, 0, stream>>>(row, cursor, N);
  k_pos<<<(E + 255) / 256, 256, 0, stream>>>(dst, cursor, pos, E);

  k_node<<<((size_t)N * 64 + 255) / 256, 256, 0, stream>>>(x, W_node, b_node, hA, N);
  k_edge_mlp<<<(E + 1) / 2, 256, 0, stream>>>(edge_attr, W_ea, b_ea, W_e1, b_e1, Ahi, E);
  k_pack_b<<<(128 * 4096 + 255) / 256, 256, 0, stream>>>(W_e2, Bph);
  k_prep_wtf<<<(2 * 12288 + 255) / 256, 256, 0, stream>>>(W_ih, W_hh, WpI, WpH);
  k_prep_wl1<<<(12288 + 255) / 256, 256, 0, stream>>>(W_l1, Wp1);

  float* hcur = hA;
  float* hnxt = hB;
  int gconv = (E + 127) / 128;
  int ngru = (N + 63) / 64;
  for (int it = 0; it < 3; ++it) {
    k_conv_fused<<<gconv, 256, 0, stream>>>(Ahi, Bph, b_e2, hcur, src, pos, msgp, E);
    k_gru_mfma<<<ngru, 256, 0, stream>>>(msgp, row, conv_bias, WpI, WpH,
                                         b_ih, b_hh, hcur, hnxt, N);
    float* tmp = hcur; hcur = hnxt; hnxt = tmp;
  }
  k_final_mfma<<<(E3 + 63) / 64, 256, 0, stream>>>(hcur, edge_attr3, edge_index3, Wp1,
                                                   b_l1, W_l2, b_l2, (float*)d_out, E3);
}

// Round 4
// 423.965 us; speedup vs baseline: 1.2289x; 1.1505x over previous
//
#include <hip/hip_runtime.h>

typedef unsigned short u16;
typedef unsigned int u32;
typedef __attribute__((ext_vector_type(8))) short short8v;
typedef __attribute__((ext_vector_type(4))) float float4v;

__device__ __forceinline__ float sigm(float x) { return 1.0f / (1.0f + __expf(-x)); }
__device__ __forceinline__ u16 f2bf(float f) {
  u32 u = __float_as_uint(f);
  u32 r = (u + 0x7fffu + ((u >> 16) & 1u)) >> 16;
  return (u16)r;
}
__device__ __forceinline__ float bf2f(u16 w) { return __uint_as_float(((u32)w) << 16); }

__global__ void k_zero_i(int* __restrict__ p, int n) {
  int i = blockIdx.x * blockDim.x + threadIdx.x;
  if (i < n) p[i] = 0;
}

__global__ void k_cnt(const int* __restrict__ dst, int* __restrict__ cnt, int E) {
  int e = blockIdx.x * blockDim.x + threadIdx.x;
  if (e < E) atomicAdd(&cnt[dst[e]], 1);
}

// --- parallel scan (r22): scan1 block sums -> scan2 scan of 98 sums -> scan3 local scan ---
__global__ void k_scan1(const int* __restrict__ cnt, int* __restrict__ bsum, int N) {
  __shared__ int ws[4];
  int t = threadIdx.x;
  int i = blockIdx.x * 256 + t;
  int v = (i < N) ? cnt[i] : 0;
  int s = v;
  for (int off = 1; off < 64; off <<= 1) s += __shfl_xor(s, off);
  int wid = t >> 6, lane = t & 63;
  if (lane == 0) ws[wid] = s;
  __syncthreads();
  if (t == 0) bsum[blockIdx.x] = ws[0] + ws[1] + ws[2] + ws[3];
}

__global__ void k_scan2(int* __restrict__ bsum, int* __restrict__ row, int nb, int N) {
  __shared__ int s[256];
  int t = threadIdx.x;
  if (t < nb) s[t] = bsum[t];
  __syncthreads();
  if (t == 0) {
    int run = 0;
    for (int i = 0; i < nb; ++i) { int x = s[i]; s[i] = run; run += x; }
    row[N] = run;
  }
  __syncthreads();
  if (t < nb) bsum[t] = s[t];
}

__global__ void k_scan3(const int* __restrict__ cnt, const int* __restrict__ bsum,
                        int* __restrict__ row, int* __restrict__ cursor, int N) {
  __shared__ int ws[4];
  int t = threadIdx.x;
  int i = blockIdx.x * 256 + t;
  int v = (i < N) ? cnt[i] : 0;
  int lane = t & 63, wid = t >> 6;
  int incl = v;
  for (int off = 1; off < 64; off <<= 1) {
    int u = __shfl_up(incl, off);
    if (lane >= off) incl += u;
  }
  if (lane == 63) ws[wid] = incl;
  __syncthreads();
  int woff = bsum[blockIdx.x];
  for (int w = 0; w < wid; ++w) woff += ws[w];
  int excl = woff + incl - v;
  if (i < N) { row[i] = excl; cursor[i] = excl; }
}

// pos[e] = CSR slot of edge e among edges with same dst (counting sort position)
__global__ void k_pos(const int* __restrict__ dst, int* __restrict__ cursor,
                      int* __restrict__ pos, int E) {
  int e = blockIdx.x * blockDim.x + threadIdx.x;
  if (e < E) pos[e] = atomicAdd(&cursor[dst[e]], 1);
}

// h[n,f] = relu(sum_k x[n,k] * W_node[k,f] + b_node[f])   [verified r5-r18]
__global__ void k_node(const float* __restrict__ x, const float* __restrict__ Wn,
                       const float* __restrict__ bn, float* __restrict__ h, int N) {
  int tid = blockIdx.x * blockDim.x + threadIdx.x;
  if (tid >= N * 64) return;
  int n = tid >> 6, f = tid & 63;
  float acc = bn[f];
  for (int k = 0; k < 8; ++k) acc += x[(size_t)n * 8 + k] * Wn[k * 64 + f];
  h[tid] = fmaxf(acc, 0.0f);
}

// hmid -> plain bf16; 2 edges/block, ea computed once in LDS   [verified r18]
__global__ __launch_bounds__(256) void k_edge_mlp(
    const float* __restrict__ ea_in, const float* __restrict__ Wea,
    const float* __restrict__ bea, const float* __restrict__ We1,
    const float* __restrict__ be1, u16* __restrict__ Ahi, int E) {
  __shared__ float att[2][19];
  __shared__ float ea[2][12];
  int half = threadIdx.x >> 7;
  int t = threadIdx.x & 127;
  int e = blockIdx.x * 2 + half;
  bool real = (e < E);
  int ee = real ? e : E - 1;
  if (t < 19) att[half][t] = ea_in[(size_t)ee * 19 + t];
  __syncthreads();
  if (t < 12) {
    float a = bea[t];
#pragma unroll
    for (int k = 0; k < 19; ++k) a += att[half][k] * Wea[k * 12 + t];
    ea[half][t] = fmaxf(a, 0.0f);
  }
  __syncthreads();
  float a = be1[t];
#pragma unroll
  for (int j = 0; j < 12; ++j) a += ea[half][j] * We1[j * 128 + t];
  if (real) Ahi[(size_t)e * 128 + t] = f2bf(fmaxf(a, 0.0f));
}

// Pack W_e2 into MFMA-fragment-ordered bf16   [verified r9-r18]
__global__ void k_pack_b(const float* __restrict__ W2, u16* __restrict__ Bph) {
  int tid = blockIdx.x * blockDim.x + threadIdx.x;
  if (tid >= 128 * 4096) return;
  int j = tid & 7;
  int lane = (tid >> 3) & 63;
  int nt = (tid >> 9) & 3;
  int ks = (tid >> 11) & 3;
  int d = tid >> 13;
  int c = lane & 15, q = lane >> 4;
  int k = ks * 32 + q * 8 + j;
  int n = d * 64 + nt * 16 + c;
  Bph[tid] = f2bf(W2[(size_t)k * 4096 + n]);
}

// Pack GRU weights into MFMA B-fragment order   [verified r16-r18]
__global__ void k_prep_wtf(const float* __restrict__ Wih, const float* __restrict__ Whh,
                           u16* __restrict__ WpI, u16* __restrict__ WpH) {
  int tid = blockIdx.x * blockDim.x + threadIdx.x;
  if (tid >= 2 * 12288) return;
  int w = tid / 12288;
  int r = tid - w * 12288;
  int jj = r & 7;
  int lane = (r >> 3) & 63;
  int t = r >> 9;
  int nt = t % 12, ks = t / 12;
  int c = lane & 15, q = lane >> 4;
  int j = nt * 16 + c;
  int k = ks * 32 + q * 8 + jj;
  const float* W = w ? Whh : Wih;
  u16* Wp = w ? WpH : WpI;
  Wp[r] = f2bf(W[j * 64 + k]);
}

// Pack W_l1 (72x128, zero-padded K to 96) into MFMA B-fragment order
__global__ void k_prep_wl1(const float* __restrict__ Wl1, u16* __restrict__ Wp1) {
  int tid = blockIdx.x * blockDim.x + threadIdx.x;
  if (tid >= 3 * 8 * 64 * 8) return;
  int j = tid & 7;
  int lane = (tid >> 3) & 63;
  int nt = (tid >> 9) & 7;
  int ks = tid >> 12;
  int c = lane & 15, q = lane >> 4;
  int k = ks * 32 + q * 8 + j;
  int n = nt * 16 + c;
  Wp1[tid] = f2bf((k < 72) ? Wl1[k * 128 + n] : 0.0f);
}

// Fused conv, r22: 3-buffer counted-vmcnt schedule (T3/T4).
//  - ONE raw s_barrier per d-iter; s_waitcnt vmcnt(4) keeps stage(d+1) in flight
//    across the barrier (never drain to 0 in the loop)
//  - stage(d+2) issued post-barrier (safe: barrier proves all waves finished
//    compute(d-1), the last reader of that buffer)
//  - hsT halved to [32][132] f32 with one refresh at dl==32 (LDS budget)
// LDS = 49152(B x3) + 16896(hsT) + 8192(sb2h) = 74240 B -> 2 blk/CU.
__global__ __launch_bounds__(256, 2) void k_conv_fused(
    const u16* __restrict__ Ahi, const u16* __restrict__ Bph,
    const float* __restrict__ b2, const float* __restrict__ h,
    const int* __restrict__ src, const int* __restrict__ pos,
    float* __restrict__ msgp, int E) {
  __shared__ __align__(16) u16 sB[3][8192];     // 3 x 16 KB B panels
  __shared__ __align__(16) float hsT[32 * 132]; // h[src[e], d] transposed, half d-range
  __shared__ __align__(16) u16 sb2h[4096];      // b2 as bf16
  int m0 = blockIdx.x * 128;
  int tid = threadIdx.x;
  int wave = tid >> 6, lane = tid & 63;
  int mw = wave >> 1, fw = wave & 1;
  int c = lane & 15, q = lane >> 4;

  auto stageB = [&](int d, int b) {
    const u16* gp = Bph + (size_t)d * 8192 + wave * 2048 + lane * 8;
    u16* lp = &sB[b][wave * 2048];
#pragma unroll
    for (int i = 0; i < 4; ++i)
      __builtin_amdgcn_global_load_lds(
          (const __attribute__((address_space(1))) unsigned int*)(gp + i * 512),
          (__attribute__((address_space(3))) unsigned int*)(lp + i * 512), 16, 0, 0);
  };
  // transposed h-stage for d in [dbase, dbase+32)
  auto loadHsT = [&](int dbase) {
#pragma unroll
    for (int p = 0; p < 4; ++p) {
      int slot = p * 256 + tid;
      int r = slot >> 3, s = slot & 7;  // edge r, d-quad s
      int ge = m0 + r;
      if (ge >= E) ge = E - 1;
      int sn = src[ge];
      float4 v = *(const float4*)(h + (size_t)sn * 64 + dbase + s * 4);
      hsT[(s * 4 + 0) * 132 + r] = v.x;
      hsT[(s * 4 + 1) * 132 + r] = v.y;
      hsT[(s * 4 + 2) * 132 + r] = v.z;
      hsT[(s * 4 + 3) * 132 + r] = v.w;
    }
  };

  stageB(0, 0);
  stageB(1, 1);

  // A fragments: 4 m-tiles x 4 k-slices, global->reg, held for whole kernel
  short8v afr[4][4];
#pragma unroll
  for (int mt = 0; mt < 4; ++mt) {
    int gr = m0 + mw * 64 + mt * 16 + c;
    if (gr >= E) gr = E - 1;
    const u16* ap = Ahi + (size_t)gr * 128 + q * 8;
#pragma unroll
    for (int ks = 0; ks < 4; ++ks) afr[mt][ks] = *(const short8v*)(ap + ks * 32);
  }

  loadHsT(0);
  {
    int t16 = tid * 16;
#pragma unroll
    for (int u = 0; u < 4; ++u) {
      float4 v = *(const float4*)(b2 + t16 + u * 4);
      sb2h[t16 + u * 4 + 0] = f2bf(v.x);
      sb2h[t16 + u * 4 + 1] = f2bf(v.y);
      sb2h[t16 + u * 4 + 2] = f2bf(v.z);
      sb2h[t16 + u * 4 + 3] = f2bf(v.w);
    }
  }
  __syncthreads();  // full drain: panels 0,1 + hsT + sb2h ready; vmcnt clean slate

  float msg[4][2][4];
#pragma unroll
  for (int mt = 0; mt < 4; ++mt)
#pragma unroll
    for (int nt = 0; nt < 2; ++nt)
#pragma unroll
      for (int r = 0; r < 4; ++r) msg[mt][nt][r] = 0.0f;

  int cur = 0;   // buffer holding panel dl
  int nx2 = 2;   // buffer for panel dl+2
  for (int dl = 0; dl < 64; ++dl) {
    // panel dl complete when <=4 vm ops outstanding (only stage(dl+1) in flight)
    if (dl < 63) asm volatile("s_waitcnt vmcnt(4)" ::: "memory");
    else         asm volatile("s_waitcnt vmcnt(0)" ::: "memory");
    __builtin_amdgcn_s_barrier();
    asm volatile("" ::: "memory");
    if (dl == 32) {  // hsT refresh for d in [32,64) (rare full drain, once)
      loadHsT(32);
      asm volatile("s_waitcnt vmcnt(0) lgkmcnt(0)" ::: "memory");
      __builtin_amdgcn_s_barrier();
      asm volatile("" ::: "memory");
    }
    if (dl < 62) stageB(dl + 2, nx2);  // post-barrier: overwrite-safe

    float b2v0 = bf2f(sb2h[dl * 64 + fw * 32 + c]);
    float b2v1 = bf2f(sb2h[dl * 64 + fw * 32 + 16 + c]);
    float4v acc[4][2];
#pragma unroll
    for (int mt = 0; mt < 4; ++mt)
#pragma unroll
      for (int nt = 0; nt < 2; ++nt) acc[mt][nt] = (float4v){0.f, 0.f, 0.f, 0.f};
    __builtin_amdgcn_s_setprio(1);
#pragma unroll
    for (int ks = 0; ks < 4; ++ks) {
      short8v b0 = *(const short8v*)(&sB[cur][ks * 2048 + fw * 1024 + lane * 8]);
      short8v b1 = *(const short8v*)(&sB[cur][ks * 2048 + fw * 1024 + 512 + lane * 8]);
#pragma unroll
      for (int mt = 0; mt < 4; ++mt) {
        acc[mt][0] = __builtin_amdgcn_mfma_f32_16x16x32_bf16(afr[mt][ks], b0, acc[mt][0], 0, 0, 0);
        acc[mt][1] = __builtin_amdgcn_mfma_f32_16x16x32_bf16(afr[mt][ks], b1, acc[mt][1], 0, 0, 0);
      }
    }
    __builtin_amdgcn_s_setprio(0);
    int dlh = dl & 31;
#pragma unroll
    for (int mt = 0; mt < 4; ++mt) {
      float4 hd4 = *(const float4*)(&hsT[dlh * 132 + mw * 64 + mt * 16 + q * 4]);
      float hd[4] = {hd4.x, hd4.y, hd4.z, hd4.w};
#pragma unroll
      for (int r = 0; r < 4; ++r) {
        msg[mt][0][r] += hd[r] * (acc[mt][0][r] + b2v0);
        msg[mt][1][r] += hd[r] * (acc[mt][1][r] + b2v1);
      }
    }
    cur = (cur == 2) ? 0 : cur + 1;
    nx2 = (nx2 == 2) ? 0 : nx2 + 1;
  }

  // stores pre-permuted to CSR slot order: GRU reads contiguous rows
#pragma unroll
  for (int mt = 0; mt < 4; ++mt) {
#pragma unroll
    for (int r = 0; r < 4; ++r) {
      int e = m0 + mw * 64 + mt * 16 + q * 4 + r;
      if (e < E) {
        int pe = pos[e];
        float* mp = msgp + (size_t)pe * 64 + fw * 32 + c;
#pragma unroll
        for (int nt = 0; nt < 2; ++nt) mp[nt * 16] = msg[mt][nt][r];
      }
    }
  }
}

// MFMA GRU, r22: float4 gather (thread = node x f-quad), row[] staged in LDS.
__global__ __launch_bounds__(256, 2) void k_gru_mfma(
    const float* __restrict__ msgp, const int* __restrict__ row,
    const float* __restrict__ cb, const u16* __restrict__ WpI,
    const u16* __restrict__ WpH, const float* __restrict__ bih,
    const float* __restrict__ bhh, const float* __restrict__ hin,
    float* __restrict__ hout, int N) {
  __shared__ __align__(16) u16 sM[64 * 72];
  __shared__ __align__(16) u16 sH[64 * 72];
  __shared__ __align__(16) float sHf[64 * 68];
  __shared__ int sRow[65];
  int n0 = blockIdx.x * 64;
  int tid = threadIdx.x;
  if (tid < 65) {
    int idx = n0 + tid;
    sRow[tid] = row[(idx <= N) ? idx : N];
  }
  __syncthreads();
  {
    int nl = tid >> 4, fq = tid & 15;
    float4 cbv = *(const float4*)(cb + fq * 4);
#pragma unroll
    for (int pass = 0; pass < 4; ++pass) {
      int n = pass * 16 + nl;
      int gn = n0 + n;
      bool real = (gn < N);
      int b0 = sRow[n], b1 = sRow[n + 1];
      if (!real) b1 = b0;
      float4 av = {0.f, 0.f, 0.f, 0.f};
      for (int j = b0; j < b1; ++j) {
        float4 mv = *(const float4*)(msgp + (size_t)j * 64 + fq * 4);
        av.x += mv.x; av.y += mv.y; av.z += mv.z; av.w += mv.w;
      }
      float cf = fmaxf((float)(b1 - b0), 1.0f);
      int hgn = real ? gn : N - 1;
      float4 hv = *(const float4*)(hin + (size_t)hgn * 64 + fq * 4);
      float m0v = fmaxf(av.x / cf + cbv.x, 0.0f);
      float m1v = fmaxf(av.y / cf + cbv.y, 0.0f);
      float m2v = fmaxf(av.z / cf + cbv.z, 0.0f);
      float m3v = fmaxf(av.w / cf + cbv.w, 0.0f);
      ushort4 mu; mu.x = f2bf(m0v); mu.y = f2bf(m1v); mu.z = f2bf(m2v); mu.w = f2bf(m3v);
      ushort4 hu; hu.x = f2bf(hv.x); hu.y = f2bf(hv.y); hu.z = f2bf(hv.z); hu.w = f2bf(hv.w);
      *(ushort4*)(&sM[n * 72 + fq * 4]) = mu;
      *(ushort4*)(&sH[n * 72 + fq * 4]) = hu;
      *(float4*)(&sHf[n * 68 + fq * 4]) = hv;
    }
  }
  __syncthreads();
  int wave = tid >> 6, lane = tid & 63;
  int c = lane & 15, q = lane >> 4;
  short8v am[2], ah[2];
#pragma unroll
  for (int ks = 0; ks < 2; ++ks) {
    am[ks] = *(const short8v*)(&sM[(wave * 16 + c) * 72 + ks * 32 + q * 8]);
    ah[ks] = *(const short8v*)(&sH[(wave * 16 + c) * 72 + ks * 32 + q * 8]);
  }
  float4v accRZ[8], accN[4], accHN[4];
#pragma unroll
  for (int i = 0; i < 8; ++i) accRZ[i] = (float4v){0.f, 0.f, 0.f, 0.f};
#pragma unroll
  for (int i = 0; i < 4; ++i) {
    accN[i] = (float4v){0.f, 0.f, 0.f, 0.f};
    accHN[i] = (float4v){0.f, 0.f, 0.f, 0.f};
  }
#pragma unroll
  for (int ks = 0; ks < 2; ++ks) {
#pragma unroll
    for (int nt = 0; nt < 8; ++nt) {
      short8v bI = *(const short8v*)(WpI + ((size_t)(ks * 12 + nt) * 64 + lane) * 8);
      short8v bH = *(const short8v*)(WpH + ((size_t)(ks * 12 + nt) * 64 + lane) * 8);
      accRZ[nt] = __builtin_amdgcn_mfma_f32_16x16x32_bf16(am[ks], bI, accRZ[nt], 0, 0, 0);
      accRZ[nt] = __builtin_amdgcn_mfma_f32_16x16x32_bf16(ah[ks], bH, accRZ[nt], 0, 0, 0);
    }
#pragma unroll
    for (int nt = 0; nt < 4; ++nt) {
      short8v bI = *(const short8v*)(WpI + ((size_t)(ks * 12 + 8 + nt) * 64 + lane) * 8);
      short8v bH = *(const short8v*)(WpH + ((size_t)(ks * 12 + 8 + nt) * 64 + lane) * 8);
      accN[nt] = __builtin_amdgcn_mfma_f32_16x16x32_bf16(am[ks], bI, accN[nt], 0, 0, 0);
      accHN[nt] = __builtin_amdgcn_mfma_f32_16x16x32_bf16(ah[ks], bH, accHN[nt], 0, 0, 0);
    }
  }
#pragma unroll
  for (int nt = 0; nt < 4; ++nt) {
    int f = nt * 16 + c;
    float brz_r = bih[f] + bhh[f];
    float brz_z = bih[64 + f] + bhh[64 + f];
    float bin = bih[128 + f];
    float bhn = bhh[128 + f];
#pragma unroll
    for (int r = 0; r < 4; ++r) {
      int nl = wave * 16 + q * 4 + r;
      int gn = n0 + nl;
      float rr = sigm(accRZ[nt][r] + brz_r);
      float zz = sigm(accRZ[nt + 4][r] + brz_z);
      float ng = tanhf(accN[nt][r] + bin + rr * (accHN[nt][r] + bhn));
      float hv = sHf[nl * 68 + f];
      if (gn < N) hout[(size_t)gn * 64 + f] = (1.0f - zz) * ng + zz * hv;
    }
  }
}

// MFMA final MLP: 64 edges/block   [verified r18]
__global__ __launch_bounds__(256) void k_final_mfma(
    const float* __restrict__ h, const float* __restrict__ ea3,
    const int* __restrict__ idx3, const u16* __restrict__ Wp1,
    const float* __restrict__ bl1, const float* __restrict__ Wl2,
    const float* __restrict__ bl2, float* __restrict__ out, int E3) {
  __shared__ __align__(16) u16 sF[64 * 104];
  int e0 = blockIdx.x * 64;
  int tid = threadIdx.x;
  {
    int er = tid >> 2;
    int part = tid & 3;
    int ge = e0 + er;
    int gc = (ge < E3) ? ge : E3 - 1;
    int a = idx3[gc], b = idx3[E3 + gc];
    for (int kk = part * 24; kk < part * 24 + 24; ++kk) {
      float v;
      if (kk < 64) v = 0.5f * (h[(size_t)a * 64 + kk] + h[(size_t)b * 64 + kk]);
      else if (kk < 72) v = ea3[(size_t)gc * 8 + (kk - 64)];
      else v = 0.0f;
      sF[er * 104 + kk] = f2bf(v);
    }
  }
  __syncthreads();
  int wave = tid >> 6, lane = tid & 63;
  int c = lane & 15, q = lane >> 4;
  float4v acc[8];
#pragma unroll
  for (int nt = 0; nt < 8; ++nt) acc[nt] = (float4v){0.f, 0.f, 0.f, 0.f};
#pragma unroll
  for (int ks = 0; ks < 3; ++ks) {
    short8v af = *(const short8v*)(&sF[(wave * 16 + c) * 104 + ks * 32 + q * 8]);
#pragma unroll
    for (int nt = 0; nt < 8; ++nt) {
      short8v bf = *(const short8v*)(Wp1 + ((size_t)(ks * 8 + nt) * 64 + lane) * 8);
      acc[nt] = __builtin_amdgcn_mfma_f32_16x16x32_bf16(af, bf, acc[nt], 0, 0, 0);
    }
  }
  float v[4] = {0.f, 0.f, 0.f, 0.f};
#pragma unroll
  for (int nt = 0; nt < 8; ++nt) {
    int n = nt * 16 + c;
    float b1 = bl1[n];
    float w2 = Wl2[n];
#pragma unroll
    for (int r = 0; r < 4; ++r) v[r] += fmaxf(acc[nt][r] + b1, 0.0f) * w2;
  }
#pragma unroll
  for (int off = 1; off < 16; off <<= 1) {
#pragma unroll
    for (int r = 0; r < 4; ++r) v[r] += __shfl_xor(v[r], off);
  }
  if (c == 0) {
    float b2v = bl2[0];
#pragma unroll
    for (int r = 0; r < 4; ++r) {
      int e = e0 + wave * 16 + q * 4 + r;
      if (e < E3) out[e] = v[r] + b2v;
    }
  }
}

extern "C" void kernel_launch(void* const* d_in, const int* in_sizes, int n_in,
                              void* d_out, int out_size, void* d_ws, size_t ws_size,
                              hipStream_t stream) {
  const float* x          = (const float*)d_in[0];
  const float* edge_attr  = (const float*)d_in[1];
  const float* edge_attr3 = (const float*)d_in[2];
  const int*   edge_index = (const int*)d_in[3];
  const int*   edge_index3= (const int*)d_in[4];
  const float* W_node = (const float*)d_in[5];
  const float* b_node = (const float*)d_in[6];
  const float* W_ea   = (const float*)d_in[7];
  const float* b_ea   = (const float*)d_in[8];
  const float* W_e1   = (const float*)d_in[9];
  const float* b_e1   = (const float*)d_in[10];
  const float* W_e2   = (const float*)d_in[11];
  const float* b_e2   = (const float*)d_in[12];
  const float* conv_bias = (const float*)d_in[13];
  const float* W_ih   = (const float*)d_in[14];
  const float* b_ih   = (const float*)d_in[15];
  const float* W_hh   = (const float*)d_in[16];
  const float* b_hh   = (const float*)d_in[17];
  const float* W_l1   = (const float*)d_in[18];
  const float* b_l1   = (const float*)d_in[19];
  const float* W_l2   = (const float*)d_in[20];
  const float* b_l2   = (const float*)d_in[21];

  int N  = in_sizes[0] / 8;
  int E  = in_sizes[1] / 19;
  int E3 = in_sizes[2] / 8;

  char* p = (char*)d_ws;
  auto carve = [&](size_t bytes) -> void* {
    char* q = p;
    p += (bytes + 255) & ~(size_t)255;
    return (void*)q;
  };
  float* hA    = (float*)carve((size_t)N * 64 * 4);
  float* hB    = (float*)carve((size_t)N * 64 * 4);
  float* msgp  = (float*)carve((size_t)E * 64 * 4);
  int*   cnt   = (int*)carve((size_t)N * 4);
  int*   row   = (int*)carve((size_t)(N + 1) * 4);
  int*   cursor= (int*)carve((size_t)N * 4);
  int*   pos   = (int*)carve((size_t)E * 4);
  int*   bsum  = (int*)carve(256 * 4);
  u16*   Ahi   = (u16*)carve((size_t)E * 128 * 2);
  u16*   Bph   = (u16*)carve((size_t)128 * 4096 * 2);
  u16*   WpI   = (u16*)carve(12288 * 2);
  u16*   WpH   = (u16*)carve(12288 * 2);
  u16*   Wp1   = (u16*)carve(12288 * 2);

  const int* src = edge_index;
  const int* dst = edge_index + E;

  int nb = (N + 255) / 256;
  // CSR build (once): cnt -> row (parallel scan) -> pos (counting-sort slot)
  k_zero_i<<<(N + 255) / 256, 256, 0, stream>>>(cnt, N);
  k_cnt<<<(E + 255) / 256, 256, 0, stream>>>(dst, cnt, E);
  k_scan1<<<nb, 256, 0, stream>>>(cnt, bsum, N);
  k_scan2<<<1, 256, 0, stream>>>(bsum, row, nb, N);
  k_scan3<<<nb, 256, 0, stream>>>(cnt, bsum, row, cursor, N);
  k_pos<<<(E + 255) / 256, 256, 0, stream>>>(dst, cursor, pos, E);

  k_node<<<((size_t)N * 64 + 255) / 256, 256, 0, stream>>>(x, W_node, b_node, hA, N);
  k_edge_mlp<<<(E + 1) / 2, 256, 0, stream>>>(edge_attr, W_ea, b_ea, W_e1, b_e1, Ahi, E);
  k_pack_b<<<(128 * 4096 + 255) / 256, 256, 0, stream>>>(W_e2, Bph);
  k_prep_wtf<<<(2 * 12288 + 255) / 256, 256, 0, stream>>>(W_ih, W_hh, WpI, WpH);
  k_prep_wl1<<<(12288 + 255) / 256, 256, 0, stream>>>(W_l1, Wp1);

  float* hcur = hA;
  float* hnxt = hB;
  int gconv = (E + 127) / 128;
  int ngru = (N + 63) / 64;
  for (int it = 0; it < 3; ++it) {
    k_conv_fused<<<gconv, 256, 0, stream>>>(Ahi, Bph, b_e2, hcur, src, pos, msgp, E);
    k_gru_mfma<<<ngru, 256, 0, stream>>>(msgp, row, conv_bias, WpI, WpH,
                                         b_ih, b_hh, hcur, hnxt, N);
    float* tmp = hcur; hcur = hnxt; hnxt = tmp;
  }
  k_final_mfma<<<(E3 + 63) / 64, 256, 0, stream>>>(hcur, edge_attr3, edge_index3, Wp1,
                                                   b_l1, W_l2, b_l2, (float*)d_out, E3);
}